// Round 2
// baseline (23.002 us; speedup 1.0000x reference)
//
#include <hip/hip_runtime.h>

// DiversityLoss: pose (K=32, B=32, T=64, E=63) fp32.
// feat[bt,k,e] = pose[k, b, t, e], bt = b*64+t.
// loss = sum_{bt} sum_{i<j} exp(-L1(feat[bt,i], feat[bt,j])) / (BT*K*(K-1)/2)
// Off-diagonal sum computed directly (both triangles, then halve) — the
// diagonal exp(0)=1 terms would absorb the ~1e-18 off-diagonal terms in fp32.

#define KDIM 32
#define EDIM 63
#define STRIDE 68      // padded row stride in dwords: 16B-aligned, conflict-free b128 reads
#define BT_TOTAL 2048
#define CNT 1015808.0f // 2048 * 32*31/2

__global__ __launch_bounds__(64) void divloss_pairs(const float* __restrict__ pose,
                                                    float* __restrict__ ws) {
    __shared__ float lds[KDIM * STRIDE];
    const int bt = blockIdx.x;
    const int lane = threadIdx.x;   // 0..63

    // Stage feat[bt]: 32 rows of 63 contiguous floats; pad e=63 with 0.
    #pragma unroll 4
    for (int k = 0; k < KDIM; ++k) {
        float v = 0.0f;
        if (lane < EDIM) v = pose[(k * BT_TOTAL + bt) * EDIM + lane];
        lds[k * STRIDE + lane] = v;   // lane 63 writes the zero pad
    }
    __syncthreads();

    const int ti = lane >> 3;   // 0..7 -> rows {ti, ti+8, ti+16, ti+24}
    const int tj = lane & 7;    // 0..7 -> cols {tj, tj+8, tj+16, tj+24}

    float acc[4][4];
    #pragma unroll
    for (int r = 0; r < 4; ++r)
        #pragma unroll
        for (int c = 0; c < 4; ++c) acc[r][c] = 0.0f;

    // 16 chunks of 4 e-elements (covers 0..63; e=63 is the zero pad).
    for (int ec = 0; ec < 16; ++ec) {
        float4 a[4], b[4];
        #pragma unroll
        for (int r = 0; r < 4; ++r)
            a[r] = *reinterpret_cast<const float4*>(&lds[(ti + 8 * r) * STRIDE + 4 * ec]);
        #pragma unroll
        for (int c = 0; c < 4; ++c)
            b[c] = *reinterpret_cast<const float4*>(&lds[(tj + 8 * c) * STRIDE + 4 * ec]);
        #pragma unroll
        for (int r = 0; r < 4; ++r)
            #pragma unroll
            for (int c = 0; c < 4; ++c) {
                acc[r][c] += fabsf(a[r].x - b[c].x) + fabsf(a[r].y - b[c].y)
                           + fabsf(a[r].z - b[c].z) + fabsf(a[r].w - b[c].w);
            }
    }

    // Per-lane sum of exp(-d) over its 16 pairs, EXCLUDING diagonal pairs
    // (row == col, i.e. ti==tj && r==c) so the 1.0 terms never enter the sum.
    float s = 0.0f;
    #pragma unroll
    for (int r = 0; r < 4; ++r)
        #pragma unroll
        for (int c = 0; c < 4; ++c) {
            float e = __expf(-acc[r][c]);
            s += ((ti == tj) && (r == c)) ? 0.0f : e;
        }

    // Wave-reduce (64 lanes).
    #pragma unroll
    for (int off = 32; off > 0; off >>= 1) s += __shfl_down(s, off, 64);

    if (lane == 0) ws[bt] = s * 0.5f;  // both triangles summed -> halve
}

__global__ __launch_bounds__(256) void divloss_reduce(const float* __restrict__ ws,
                                                      float* __restrict__ out) {
    __shared__ float partial[4];
    float s = 0.0f;
    for (int i = threadIdx.x; i < BT_TOTAL; i += 256) s += ws[i];
    #pragma unroll
    for (int off = 32; off > 0; off >>= 1) s += __shfl_down(s, off, 64);
    const int wave = threadIdx.x >> 6;
    if ((threadIdx.x & 63) == 0) partial[wave] = s;
    __syncthreads();
    if (threadIdx.x == 0) {
        float t = partial[0] + partial[1] + partial[2] + partial[3];
        out[0] = t * (1.0f / CNT);
    }
}

extern "C" void kernel_launch(void* const* d_in, const int* in_sizes, int n_in,
                              void* d_out, int out_size, void* d_ws, size_t ws_size,
                              hipStream_t stream) {
    const float* pose = (const float*)d_in[0];
    float* out = (float*)d_out;
    float* ws = (float*)d_ws;   // needs 2048 * 4 B

    divloss_pairs<<<BT_TOTAL, 64, 0, stream>>>(pose, ws);
    divloss_reduce<<<1, 256, 0, stream>>>(ws, out);
}

// Round 3
// 16.668 us; speedup vs baseline: 1.3800x; 1.3800x over previous
//
#include <hip/hip_runtime.h>

// DiversityLoss: pose (K=32, B=32, T=64, E=63) fp32.
// feat[bt,k,e] = pose[k, b, t, e], bt = b*64+t.
// loss = sum_{bt} sum_{i<j} exp(-L1(feat[bt,i], feat[bt,j])) / (BT*K*(K-1)/2)
// Off-diagonal sum computed directly (both triangles, then halve) — diagonal
// exp(0)=1 terms would absorb the ~1e-18 off-diagonal terms in fp32.
//
// Structure: 1 block (256 thr, 4 waves) per bt slice. The 4 waves split the
// e-dimension (16 elems each) so the 4x4 register tile (0.5 LDS-reads/pair)
// is preserved while occupancy quadruples vs the 1-wave-per-block version.
// Per-wave partial acc[4][4] are combined through a conflict-free
// part[entry][wave][lane] LDS layout that aliases the feat tile.

#define KDIM 32
#define EDIM 63
#define STRIDE 68      // feat row stride (dwords): 16B-aligned; 68%32=4 -> ti-groups spread over all banks
#define BT_TOTAL 2048
#define CNT 1015808.0f // 2048 * 32*31/2

__global__ __launch_bounds__(256) void divloss_pairs(const float* __restrict__ pose,
                                                     float* __restrict__ ws) {
    // 16 KB: feat tile (32*68 = 2176 dwords) aliases the low part; the
    // part[16][4][64] exchange buffer (4096 dwords) reuses it after a sync.
    __shared__ float smem[4096];
    __shared__ float wsum[4];
    float* feat = smem;
    float* part = smem;

    const int bt = blockIdx.x;
    const int wv = threadIdx.x >> 6;    // 0..3
    const int lane = threadIdx.x & 63;  // 0..63

    // Stage feat[bt]: wave wv loads rows 8*wv .. 8*wv+7 (63 floats each, pad e=63 with 0).
    #pragma unroll
    for (int r = 0; r < 8; ++r) {
        const int k = 8 * wv + r;
        float v = 0.0f;
        if (lane < EDIM) v = pose[(k * BT_TOTAL + bt) * EDIM + lane];
        feat[k * STRIDE + lane] = v;    // lane 63 writes the zero pad
    }
    __syncthreads();

    const int ti = lane >> 3;   // rows {ti, ti+8, ti+16, ti+24}
    const int tj = lane & 7;    // cols {tj, tj+8, tj+16, tj+24}

    float acc[4][4];
    #pragma unroll
    for (int r = 0; r < 4; ++r)
        #pragma unroll
        for (int c = 0; c < 4; ++c) acc[r][c] = 0.0f;

    // Wave wv covers e-chunks 4*wv .. 4*wv+3 (16 e-elems; wave 3 includes the pad).
    #pragma unroll
    for (int i = 0; i < 4; ++i) {
        const int ec = 4 * wv + i;
        float4 a[4], b[4];
        #pragma unroll
        for (int r = 0; r < 4; ++r)
            a[r] = *reinterpret_cast<const float4*>(&feat[(ti + 8 * r) * STRIDE + 4 * ec]);
        #pragma unroll
        for (int c = 0; c < 4; ++c)
            b[c] = *reinterpret_cast<const float4*>(&feat[(tj + 8 * c) * STRIDE + 4 * ec]);
        #pragma unroll
        for (int r = 0; r < 4; ++r)
            #pragma unroll
            for (int c = 0; c < 4; ++c) {
                acc[r][c] += fabsf(a[r].x - b[c].x) + fabsf(a[r].y - b[c].y)
                           + fabsf(a[r].z - b[c].z) + fabsf(a[r].w - b[c].w);
            }
    }

    __syncthreads();   // all feat reads done; safe to overwrite with partials

    // part[entry e=r*4+c][src wave][lane] — stride-1 across lanes, conflict-free.
    #pragma unroll
    for (int r = 0; r < 4; ++r)
        #pragma unroll
        for (int c = 0; c < 4; ++c)
            part[((r * 4 + c) * 4 + wv) * 64 + lane] = acc[r][c];
    __syncthreads();

    // Wave wv finalizes entries r=wv, c=0..3: sum the 4 per-wave partials,
    // exp, mask diagonal pairs (i==j <=> ti==tj && r==c), accumulate.
    float s = 0.0f;
    #pragma unroll
    for (int c = 0; c < 4; ++c) {
        float d = 0.0f;
        #pragma unroll
        for (int sw = 0; sw < 4; ++sw)
            d += part[((wv * 4 + c) * 4 + sw) * 64 + lane];
        float e = __expf(-d);
        s += ((ti == tj) && (c == wv)) ? 0.0f : e;
    }

    #pragma unroll
    for (int off = 32; off > 0; off >>= 1) s += __shfl_down(s, off, 64);
    if (lane == 0) wsum[wv] = s;
    __syncthreads();

    if (threadIdx.x == 0)
        ws[bt] = 0.5f * (wsum[0] + wsum[1] + wsum[2] + wsum[3]);
}

__global__ __launch_bounds__(256) void divloss_reduce(const float* __restrict__ ws,
                                                      float* __restrict__ out) {
    __shared__ float partial[4];
    float s = 0.0f;
    for (int i = threadIdx.x; i < BT_TOTAL; i += 256) s += ws[i];
    #pragma unroll
    for (int off = 32; off > 0; off >>= 1) s += __shfl_down(s, off, 64);
    const int wave = threadIdx.x >> 6;
    if ((threadIdx.x & 63) == 0) partial[wave] = s;
    __syncthreads();
    if (threadIdx.x == 0) {
        float t = partial[0] + partial[1] + partial[2] + partial[3];
        out[0] = t * (1.0f / CNT);
    }
}

extern "C" void kernel_launch(void* const* d_in, const int* in_sizes, int n_in,
                              void* d_out, int out_size, void* d_ws, size_t ws_size,
                              hipStream_t stream) {
    const float* pose = (const float*)d_in[0];
    float* out = (float*)d_out;
    float* ws = (float*)d_ws;   // needs 2048 * 4 B

    divloss_pairs<<<BT_TOTAL, 256, 0, stream>>>(pose, ws);
    divloss_reduce<<<1, 256, 0, stream>>>(ws, out);
}